// Round 5
// baseline (120.969 us; speedup 1.0000x reference)
//
#include <hip/hip_runtime.h>
#include <hip/hip_bf16.h>

#define NROWS 4096
#define DMODEL 256
#define NHEADS 8
#define HD 32

typedef __attribute__((ext_vector_type(8))) short short8;
typedef __attribute__((ext_vector_type(4))) float f32x4;

__device__ __forceinline__ short bf16raw(float x) {
  return (short)__builtin_bit_cast(unsigned short, __float2bfloat16(x));
}
__device__ __forceinline__ short8 cvt8(const float4 a, const float4 b) {
  short8 r;
  r[0] = bf16raw(a.x); r[1] = bf16raw(a.y); r[2] = bf16raw(a.z); r[3] = bf16raw(a.w);
  r[4] = bf16raw(b.x); r[5] = bf16raw(b.y); r[6] = bf16raw(b.z); r[7] = bf16raw(b.w);
  return r;
}

// ============ kernel 1: QKV GEMM (fp32 in, cvt in-register) + side work =====
// blocks 0..767: 64x64 gemm tiles, XCD-chunked swizzle (T1): XCD j = bid%8
//   owns row-stripes [8j,8j+8) x all 12 col-panels -> A-stripe (512 KB fp32)
//   + W panel (768 KB fp32) are read into XCD-local L2 once; re-reads are L2
//   hits. In-register fp32->bf16 cvt is bit-identical to the staged path.
// blocks 768..783: segment-bounds scan of batch_idx (consumer: attn, later).
// blocks 784..847: w_out fp32->bf16 cast     (consumer: out_ln, 2 later).
__global__ __launch_bounds__(256, 4) void gemm_qkv_f32(
    const float* __restrict__ A,     // slots [4096][256] fp32
    const float* __restrict__ W,     // w_in  [768][256]  fp32
    const float* __restrict__ bias,  // b_in  [768]
    const float* __restrict__ w_out, // [256][256] fp32
    const int* __restrict__ bidx,
    int* __restrict__ segs,
    __hip_bfloat16* __restrict__ Woutb, // [256][256] bf16
    __hip_bfloat16* __restrict__ Qo,    // [H][N][32]
    __hip_bfloat16* __restrict__ Ko,    // [H][N][32]
    __hip_bfloat16* __restrict__ Vo) {  // [H][32][N]
  const int bid = blockIdx.x;
  if (bid >= 768) {
    if (bid < 784) {
      const int r = (bid - 768) * 256 + threadIdx.x;
      const int b = bidx[r];
      if (r == 0 || bidx[r - 1] != b) segs[b] = r;
      if (r == NROWS - 1 || bidx[r + 1] != b) segs[16 + b] = r + 1;
    } else {
      const int i = ((bid - 784) * 256 + (int)threadIdx.x) * 4;
      const float4 v = *(const float4*)(w_out + i);
      __hip_bfloat162 lo, hi;
      lo.x = __float2bfloat16(v.x); lo.y = __float2bfloat16(v.y);
      hi.x = __float2bfloat16(v.z); hi.y = __float2bfloat16(v.w);
      *(__hip_bfloat162*)(Woutb + i) = lo;
      *(__hip_bfloat162*)(Woutb + i + 2) = hi;
    }
    return;
  }
  const int swz = (bid & 7) * 96 + (bid >> 3);   // bijective (768 % 8 == 0)
  const int bn = (swz % 12) * 64;
  const int wv   = threadIdx.x >> 6;
  const int lane = threadIdx.x & 63;
  const int lo16 = lane & 15;
  const int quad = lane >> 4;
  const int bm = (swz / 12) * 64 + wv * 16;

  f32x4 acc[4] = {};
  #pragma unroll
  for (int k0 = 0; k0 < 256; k0 += 32) {
    const float* ap = A + (size_t)(bm + lo16) * 256 + k0 + quad * 8;
    const short8 af = cvt8(*(const float4*)ap, *(const float4*)(ap + 4));
    #pragma unroll
    for (int ni = 0; ni < 4; ni++) {
      const float* wp = W + (size_t)(bn + ni * 16 + lo16) * 256 + k0 + quad * 8;
      const short8 bf = cvt8(*(const float4*)wp, *(const float4*)(wp + 4));
      acc[ni] = __builtin_amdgcn_mfma_f32_16x16x32_bf16(af, bf, acc[ni], 0, 0, 0);
    }
  }
  #pragma unroll
  for (int ni = 0; ni < 4; ni++) {
    const int col = bn + ni * 16 + lo16;
    const int sel = col >> 8;          // 0:Q 1:K 2:V
    const int h = (col & 255) >> 5;
    const int d = col & 31;
    const float bv = bias[col];
    #pragma unroll
    for (int r = 0; r < 4; r++) {
      const int n = bm + quad * 4 + r;
      const __hip_bfloat16 v = __float2bfloat16(acc[ni][r] + bv);
      if (sel == 0)      Qo[((size_t)h * NROWS + n) * HD + d] = v;
      else if (sel == 1) Ko[((size_t)h * NROWS + n) * HD + d] = v;
      else               Vo[((size_t)h * HD + d) * NROWS + n] = v;
    }
  }
}

// ---------------- attention: 4-way split-K flash, 64-col k-tiles -----------
// Swapped-operand QK^T (lane owns one q-row) + 64-col tiles: softmax
// bookkeeping (2 shuffle reduces, alpha bounce, rescale, __all) amortizes
// over 16 scores/lane instead of 8. setprio(1) around MFMA clusters (T5).
// Head h = bid&7 pins each head's K/V to one XCD's L2 (round-robin dispatch).
__global__ __launch_bounds__(256, 4) void attn_mfma(
    const __hip_bfloat16* __restrict__ Qb,  // [H][N][32]
    const __hip_bfloat16* __restrict__ Kb,  // [H][N][32]
    const __hip_bfloat16* __restrict__ Vt,  // [H][32][N]
    const int* __restrict__ bidx,
    const int* __restrict__ segs,
    __hip_bfloat16* __restrict__ out)       // [N][256] bf16
{
  __shared__ __align__(16) __hip_bfloat16 Plds_all[4][16][72];  // 9216 B
  __shared__ __align__(16) float alds_all[4][16];
  __shared__ float mld[4][16], lld[4][16];
  __shared__ float Old[4][16][32];
  const int wv   = threadIdx.x >> 6;
  const int lane = threadIdx.x & 63;
  const int qt   = blockIdx.x >> 3;
  const int h    = blockIdx.x & 7;
  const int r0   = qt * 16;
  const int lo16 = lane & 15;
  const int quad = lane >> 4;
  __hip_bfloat16 (*Plds)[72] = Plds_all[wv];
  float* alds = alds_all[wv];

  // per-lane q-row bounds (this lane's q-row is r0 + lo16)
  const int bq  = bidx[r0 + lo16];
  const int stq = segs[bq];
  const unsigned rng = (unsigned)(segs[16 + bq] - stq);

  const int kstart = segs[bidx[r0]] & ~63;        // 64-aligned
  const int kend   = segs[16 + bidx[r0 + 15]];
  const int ntiles = (kend - kstart + 63) >> 6;   // 64-col tiles

  const short8 qf = *(const short8*)(Qb + ((size_t)h * NROWS + r0 + lo16) * HD + quad * 8);

  f32x4 o0 = {0.f, 0.f, 0.f, 0.f}, o1 = {0.f, 0.f, 0.f, 0.f};
  float m = -1e30f, l = 0.0f;
  const float scale2 = 0.17677669529663687f * 1.4426950408889634f; // /sqrt(32)*log2e

  for (int t = wv; t < ntiles; t += 4) {
    const int c0 = kstart + t * 64;   // tile stays in [0,4096): N and kstart 64-aligned
    const __hip_bfloat16* kbase = Kb + ((size_t)h * NROWS + c0 + lo16) * HD + quad * 8;
    const short8 kf0 = *(const short8*)(kbase);
    const short8 kf1 = *(const short8*)(kbase + 16 * HD);
    const short8 kf2 = *(const short8*)(kbase + 32 * HD);
    const short8 kf3 = *(const short8*)(kbase + 48 * HD);
    const __hip_bfloat16* vbase = Vt + ((size_t)h * HD + lo16) * NROWS + c0 + quad * 8;
    const short8 vA0 = *(const short8*)(vbase);                 // d=lo16,    k 0..31
    const short8 vA1 = *(const short8*)(vbase + 32);            // d=lo16,    k 32..63
    const short8 vB0 = *(const short8*)(vbase + 16 * NROWS);    // d=16+lo16, k 0..31
    const short8 vB1 = *(const short8*)(vbase + 16 * NROWS + 32);

    const f32x4 z = {0.f, 0.f, 0.f, 0.f};
    __builtin_amdgcn_s_setprio(1);
    // swapped operands: S^T -> lane owns q-row lo16; k = c0 + g*16 + quad*4 + r
    f32x4 sv[4];
    sv[0] = __builtin_amdgcn_mfma_f32_16x16x32_bf16(kf0, qf, z, 0, 0, 0);
    sv[1] = __builtin_amdgcn_mfma_f32_16x16x32_bf16(kf1, qf, z, 0, 0, 0);
    sv[2] = __builtin_amdgcn_mfma_f32_16x16x32_bf16(kf2, qf, z, 0, 0, 0);
    sv[3] = __builtin_amdgcn_mfma_f32_16x16x32_bf16(kf3, qf, z, 0, 0, 0);
    __builtin_amdgcn_s_setprio(0);

    const int kb = c0 + quad * 4 - stq;
    float p[4][4];
    float mx = -3e38f;
    #pragma unroll
    for (int g = 0; g < 4; g++) {
      #pragma unroll
      for (int r = 0; r < 4; r++) {
        const float sc = ((unsigned)(kb + g * 16 + r) < rng) ? sv[g][r] * scale2 : -3e38f;
        p[g][r] = sc;
        mx = fmaxf(mx, sc);
      }
    }
    // reduce across the 4 lanes holding this q-row (bits 4,5 of lane id)
    mx = fmaxf(mx, __shfl_xor(mx, 16));
    mx = fmaxf(mx, __shfl_xor(mx, 32));
    const float nm = fmaxf(m, mx);
    float ps = 0.0f;
    #pragma unroll
    for (int g = 0; g < 4; g++) {
      #pragma unroll
      for (int r = 0; r < 4; r++) {
        p[g][r] = __builtin_amdgcn_exp2f(p[g][r] - nm);
        ps += p[g][r];
      }
    }
    ps += __shfl_xor(ps, 16);
    ps += __shfl_xor(ps, 32);

    const float alpha = __builtin_amdgcn_exp2f(m - nm);
    l = l * alpha + ps;
    if (!__all(nm == m)) {   // some row's max grew: rescale O (output-row layout)
      if (quad == 0) alds[lo16] = alpha;
      const f32x4 av = *(const f32x4*)&alds[quad * 4];
      #pragma unroll
      for (int r = 0; r < 4; r++) { o0[r] *= av[r]; o1[r] *= av[r]; }
    }
    m = nm;

    // P^T(lane) -> P(LDS): lane writes row q=lo16, cols g*16 + quad*4 + {0..3}
    #pragma unroll
    for (int g = 0; g < 4; g++) {
      __hip_bfloat162* pw = (__hip_bfloat162*)&Plds[lo16][g * 16 + quad * 4];
      __hip_bfloat162 a, b;
      a.x = __float2bfloat16(p[g][0]); a.y = __float2bfloat16(p[g][1]);
      b.x = __float2bfloat16(p[g][2]); b.y = __float2bfloat16(p[g][3]);
      pw[0] = a; pw[1] = b;
    }
    const short8 pf0 = *(const short8*)&Plds[lo16][quad * 8];        // k 0..31
    const short8 pf1 = *(const short8*)&Plds[lo16][32 + quad * 8];   // k 32..63
    __builtin_amdgcn_s_setprio(1);
    o0 = __builtin_amdgcn_mfma_f32_16x16x32_bf16(pf0, vA0, o0, 0, 0, 0);
    o0 = __builtin_amdgcn_mfma_f32_16x16x32_bf16(pf1, vA1, o0, 0, 0, 0);
    o1 = __builtin_amdgcn_mfma_f32_16x16x32_bf16(pf0, vB0, o1, 0, 0, 0);
    o1 = __builtin_amdgcn_mfma_f32_16x16x32_bf16(pf1, vB1, o1, 0, 0, 0);
    __builtin_amdgcn_s_setprio(0);
  }

  // ---- publish per-wave state ----
  #pragma unroll
  for (int r = 0; r < 4; r++) {
    const int row = quad * 4 + r;
    Old[wv][row][lo16]      = o0[r];
    Old[wv][row][lo16 + 16] = o1[r];
  }
  if (quad == 0) { mld[wv][lo16] = m; lld[wv][lo16] = l; }
  __syncthreads();

  // ---- merge: thread -> (row = tid>>4, cols {c, c+16}) ----
  const int row = threadIdx.x >> 4;
  const int c   = threadIdx.x & 15;
  float M = fmaxf(fmaxf(mld[0][row], mld[1][row]),
                  fmaxf(mld[2][row], mld[3][row]));
  float L = 0.f, O0 = 0.f, O1 = 0.f;
  #pragma unroll
  for (int w = 0; w < 4; w++) {
    const float e = __builtin_amdgcn_exp2f(mld[w][row] - M);
    L  += e * lld[w][row];
    O0 += e * Old[w][row][c];
    O1 += e * Old[w][row][c + 16];
  }
  const float inv = 1.0f / L;
  const int grow = r0 + row;
  out[(size_t)grow * DMODEL + h * HD + c]      = __float2bfloat16(O0 * inv);
  out[(size_t)grow * DMODEL + h * HD + 16 + c] = __float2bfloat16(O1 * inv);
}

// ---------------- out-proj + residual + LayerNorm (fused) ------------------
// 16x256 tile (row-complete), 4 waves; wave wv does cols [wv*64, +64).
// Direct-from-global frags (w_out bf16 is 128 KB, L2-resident per XCD).
__global__ __launch_bounds__(256, 4) void gemm_out_ln(
    const __hip_bfloat16* __restrict__ A,   // attnb [4096][256]
    const __hip_bfloat16* __restrict__ B,   // w_out bf16 [256][256]
    const float* __restrict__ bias,         // b_out
    const float* __restrict__ x,            // slots fp32 (residual)
    const float* __restrict__ gamma, const float* __restrict__ beta,
    float* __restrict__ out) {
  __shared__ float red1[16][4], red2[16][4];
  const int wv   = threadIdx.x >> 6;
  const int lane = threadIdx.x & 63;
  const int lo16 = lane & 15;
  const int quad = lane >> 4;
  const int r0 = blockIdx.x * 16;
  const int wn = wv * 64;

  f32x4 acc[4] = {};
  #pragma unroll
  for (int k0 = 0; k0 < 256; k0 += 32) {
    const short8 af = *(const short8*)(A + (size_t)(r0 + lo16) * 256 + k0 + quad * 8);
    #pragma unroll
    for (int ni = 0; ni < 4; ni++) {
      const short8 bf = *(const short8*)(B + (size_t)(wn + ni * 16 + lo16) * 256 + k0 + quad * 8);
      acc[ni] = __builtin_amdgcn_mfma_f32_16x16x32_bf16(af, bf, acc[ni], 0, 0, 0);
    }
  }

  // val = delta + bias + residual; per-row partial sums across this wave
  float val[4][4];
  float s1[4] = {}, s2[4] = {};
  #pragma unroll
  for (int ni = 0; ni < 4; ni++) {
    const int col = wn + ni * 16 + lo16;
    const float bv = bias[col];
    #pragma unroll
    for (int r = 0; r < 4; r++) {
      const int row = r0 + quad * 4 + r;
      const float v = acc[ni][r] + bv + x[(size_t)row * DMODEL + col];
      val[ni][r] = v;
      s1[r] += v;
      s2[r] += v * v;
    }
  }
  #pragma unroll
  for (int r = 0; r < 4; r++) {
    #pragma unroll
    for (int off = 1; off < 16; off <<= 1) {
      s1[r] += __shfl_xor(s1[r], off);
      s2[r] += __shfl_xor(s2[r], off);
    }
    if (lo16 == 0) { red1[quad * 4 + r][wv] = s1[r]; red2[quad * 4 + r][wv] = s2[r]; }
  }
  __syncthreads();
  #pragma unroll
  for (int r = 0; r < 4; r++) {
    const int lrow = quad * 4 + r;
    const float mean = (red1[lrow][0] + red1[lrow][1] + red1[lrow][2] + red1[lrow][3]) * (1.0f / DMODEL);
    const float ex2  = (red2[lrow][0] + red2[lrow][1] + red2[lrow][2] + red2[lrow][3]) * (1.0f / DMODEL);
    const float rstd = rsqrtf(fmaxf(ex2 - mean * mean, 0.0f) + 1e-5f);
    const int row = r0 + lrow;
    #pragma unroll
    for (int ni = 0; ni < 4; ni++) {
      const int col = wn + ni * 16 + lo16;
      out[(size_t)row * DMODEL + col] =
          (val[ni][r] - mean) * rstd * gamma[col] + beta[col];
    }
  }
}

extern "C" void kernel_launch(void* const* d_in, const int* in_sizes, int n_in,
                              void* d_out, int out_size, void* d_ws, size_t ws_size,
                              hipStream_t stream) {
  const float* slots  = (const float*)d_in[0];
  const int*   bidx   = (const int*)  d_in[1];
  const float* w_in   = (const float*)d_in[2];
  const float* b_in   = (const float*)d_in[3];
  const float* w_out  = (const float*)d_in[4];
  const float* b_out  = (const float*)d_in[5];
  const float* ln_g   = (const float*)d_in[6];
  const float* ln_b   = (const float*)d_in[7];
  float* out = (float*)d_out;

  char* ws = (char*)d_ws;
  __hip_bfloat16* Qb    = (__hip_bfloat16*)(ws);                // 2 MB
  __hip_bfloat16* Kb    = (__hip_bfloat16*)(ws + (2u << 20));   // 2 MB
  __hip_bfloat16* Vt    = (__hip_bfloat16*)(ws + (4u << 20));   // 2 MB
  __hip_bfloat16* attnb = (__hip_bfloat16*)(ws + (6u << 20));   // 2 MB
  __hip_bfloat16* Woutb = (__hip_bfloat16*)(ws + (8u << 20));   // 128 KB
  int*            segs  = (int*)           (ws + (9u << 20));   // 32 ints

  // 1) QKV projection (fp32 direct, in-register cvt, XCD-chunked)
  //    + segs scan + w_out bf16 cast (side blocks)
  gemm_qkv_f32<<<848, 256, 0, stream>>>(slots, w_in, b_in, w_out, bidx,
                                        segs, Woutb, Qb, Kb, Vt);
  // 2) split-K flash attention, one block per (q-tile, head)
  attn_mfma<<<(NROWS / 16) * NHEADS, 256, 0, stream>>>(Qb, Kb, Vt, bidx,
                                                       segs, attnb);
  // 3) out-proj + residual + LayerNorm, 256 blocks
  gemm_out_ln<<<NROWS / 16, 256, 0, stream>>>(attnb, Woutb, b_out, slots,
                                              ln_g, ln_b, out);
}

// Round 6
// 109.611 us; speedup vs baseline: 1.1036x; 1.1036x over previous
//
#include <hip/hip_runtime.h>
#include <hip/hip_bf16.h>

#define NROWS 4096
#define DMODEL 256
#define NHEADS 8
#define HD 32

typedef __attribute__((ext_vector_type(8))) short short8;
typedef __attribute__((ext_vector_type(4))) float f32x4;

// ---------------- prep: casts (fp32->bf16) + segment bounds ----------------
// bf16 staging de-duplicates fp32->bf16: R2/R5 both showed fp32-direct GEMM
// consumers cost ~10 us (2x L2 bytes + inner-loop cvt). Keep this dispatch.
__global__ __launch_bounds__(256) void prep_kernel(
    const float* __restrict__ slots, const float* __restrict__ w_in,
    const float* __restrict__ w_out, const int* __restrict__ bidx,
    __hip_bfloat16* __restrict__ Abf, __hip_bfloat16* __restrict__ Winb,
    __hip_bfloat16* __restrict__ Woutb, int* __restrict__ segs) {
  const int bid = blockIdx.x;
  const float* src;
  __hip_bfloat16* dst;
  int i;
  if (bid < 1024)      { src = slots; dst = Abf;   i = (bid * 256 + (int)threadIdx.x) * 4; }
  else if (bid < 1216) { src = w_in;  dst = Winb;  i = ((bid - 1024) * 256 + (int)threadIdx.x) * 4; }
  else if (bid < 1280) { src = w_out; dst = Woutb; i = ((bid - 1216) * 256 + (int)threadIdx.x) * 4; }
  else {
    const int r = (bid - 1280) * 256 + threadIdx.x;
    const int b = bidx[r];
    if (r == 0 || bidx[r - 1] != b) segs[b] = r;
    if (r == NROWS - 1 || bidx[r + 1] != b) segs[16 + b] = r + 1;
    return;
  }
  const float4 v = *(const float4*)(src + i);
  short4 o;   // single 8-byte store (halves store instructions vs 2x bfloat162)
  o.x = (short)__builtin_bit_cast(unsigned short, __float2bfloat16(v.x));
  o.y = (short)__builtin_bit_cast(unsigned short, __float2bfloat16(v.y));
  o.z = (short)__builtin_bit_cast(unsigned short, __float2bfloat16(v.z));
  o.w = (short)__builtin_bit_cast(unsigned short, __float2bfloat16(v.w));
  *(short4*)(dst + i) = o;
}

// ---------------- QKV GEMM: barrier-free, direct-from-global frags ---------
// 64x64 tile, 4 waves. 1D grid + XCD-chunked swizzle (T1). sel is UNIFORM
// per block (64-col panels don't straddle 256-col boundaries), so the
// epilogue branches once per block. V-blocks transpose their 64x64 tile
// through padded LDS -> fully coalesced 128B-run stores into Vt (the old
// direct path scattered 64 lanes across 64 distinct 8KB-strided lines).
__global__ __launch_bounds__(256, 4) void gemm_qkv(
    const __hip_bfloat16* __restrict__ A,   // [4096][256]
    const __hip_bfloat16* __restrict__ B,   // [768][256] (w_in bf16)
    const float* __restrict__ bias,         // [768]
    __hip_bfloat16* __restrict__ Qo,        // [H][N][32]
    __hip_bfloat16* __restrict__ Ko,        // [H][N][32]
    __hip_bfloat16* __restrict__ Vo) {      // [H][32][N] (transposed)
  __shared__ __align__(16) __hip_bfloat16 vt[64][72];  // 9216 B, V-blocks only
  const int bid = blockIdx.x;                    // 768 blocks
  const int swz = (bid & 7) * 96 + (bid >> 3);   // bijective (768 % 8 == 0)
  const int bn = (swz % 12) * 64;
  const int wv   = threadIdx.x >> 6;
  const int lane = threadIdx.x & 63;
  const int lo16 = lane & 15;
  const int quad = lane >> 4;
  const int bm_blk = (swz / 12) * 64;
  const int bm = bm_blk + wv * 16;

  f32x4 acc[4] = {};
  #pragma unroll
  for (int k0 = 0; k0 < 256; k0 += 32) {
    const short8 af = *(const short8*)(A + (size_t)(bm + lo16) * 256 + k0 + quad * 8);
    #pragma unroll
    for (int ni = 0; ni < 4; ni++) {
      const short8 bf = *(const short8*)(B + (size_t)(bn + ni * 16 + lo16) * 256 + k0 + quad * 8);
      acc[ni] = __builtin_amdgcn_mfma_f32_16x16x32_bf16(af, bf, acc[ni], 0, 0, 0);
    }
  }

  const int sel = bn >> 8;   // uniform per block: 0:Q 1:K 2:V
  if (sel < 2) {
    __hip_bfloat16* dst = (sel == 0) ? Qo : Ko;
    #pragma unroll
    for (int ni = 0; ni < 4; ni++) {
      const int col = bn + ni * 16 + lo16;
      const int h = (col & 255) >> 5;
      const int d = col & 31;
      const float bv = bias[col];
      #pragma unroll
      for (int r = 0; r < 4; r++) {
        const int n = bm + quad * 4 + r;
        dst[((size_t)h * NROWS + n) * HD + d] = __float2bfloat16(acc[ni][r] + bv);
      }
    }
  } else {
    // transpose 64x64 tile: vt[local_col(d)][local_n]
    #pragma unroll
    for (int ni = 0; ni < 4; ni++) {
      const float bv = bias[bn + ni * 16 + lo16];
      #pragma unroll
      for (int r = 0; r < 4; r++)
        vt[ni * 16 + lo16][wv * 16 + quad * 4 + r] = __float2bfloat16(acc[ni][r] + bv);
    }
    __syncthreads();
    const int tid = threadIdx.x;
    const int cl  = tid >> 2;          // 0..63 local col (d-dim)
    const int nch = (tid & 3) * 16;    // 16-row n chunk
    const int gcol = bn + cl;          // 512..767
    const int h = (gcol & 255) >> 5;
    const int d = gcol & 31;
    __hip_bfloat16* vdst = Vo + ((size_t)h * HD + d) * NROWS + bm_blk + nch;
    *(short8*)vdst       = *(const short8*)&vt[cl][nch];
    *(short8*)(vdst + 8) = *(const short8*)&vt[cl][nch + 8];
  }
}

// ---------------- attention: 4-way split-K flash, 64-col k-tiles -----------
// Swapped-operand QK^T (lane owns one q-row) + 64-col tiles: softmax
// bookkeeping (2 shuffle reduces, alpha bounce, rescale, __all) amortizes
// over 16 scores/lane instead of 8. setprio(1) around MFMA clusters (T5).
// Head h = bid&7 pins each head's K/V to one XCD's L2 (round-robin dispatch).
__global__ __launch_bounds__(256, 4) void attn_mfma(
    const __hip_bfloat16* __restrict__ Qb,  // [H][N][32]
    const __hip_bfloat16* __restrict__ Kb,  // [H][N][32]
    const __hip_bfloat16* __restrict__ Vt,  // [H][32][N]
    const int* __restrict__ bidx,
    const int* __restrict__ segs,
    __hip_bfloat16* __restrict__ out)       // [N][256] bf16
{
  __shared__ __align__(16) __hip_bfloat16 Plds_all[4][16][72];  // 9216 B
  __shared__ __align__(16) float alds_all[4][16];
  __shared__ float mld[4][16], lld[4][16];
  __shared__ float Old[4][16][32];
  const int wv   = threadIdx.x >> 6;
  const int lane = threadIdx.x & 63;
  const int qt   = blockIdx.x >> 3;
  const int h    = blockIdx.x & 7;
  const int r0   = qt * 16;
  const int lo16 = lane & 15;
  const int quad = lane >> 4;
  __hip_bfloat16 (*Plds)[72] = Plds_all[wv];
  float* alds = alds_all[wv];

  // per-lane q-row bounds (this lane's q-row is r0 + lo16)
  const int bq  = bidx[r0 + lo16];
  const int stq = segs[bq];
  const unsigned rng = (unsigned)(segs[16 + bq] - stq);

  const int kstart = segs[bidx[r0]] & ~63;        // 64-aligned
  const int kend   = segs[16 + bidx[r0 + 15]];
  const int ntiles = (kend - kstart + 63) >> 6;   // 64-col tiles

  const short8 qf = *(const short8*)(Qb + ((size_t)h * NROWS + r0 + lo16) * HD + quad * 8);

  f32x4 o0 = {0.f, 0.f, 0.f, 0.f}, o1 = {0.f, 0.f, 0.f, 0.f};
  float m = -1e30f, l = 0.0f;
  const float scale2 = 0.17677669529663687f * 1.4426950408889634f; // /sqrt(32)*log2e

  for (int t = wv; t < ntiles; t += 4) {
    const int c0 = kstart + t * 64;   // tile stays in [0,4096): N and kstart 64-aligned
    const __hip_bfloat16* kbase = Kb + ((size_t)h * NROWS + c0 + lo16) * HD + quad * 8;
    const short8 kf0 = *(const short8*)(kbase);
    const short8 kf1 = *(const short8*)(kbase + 16 * HD);
    const short8 kf2 = *(const short8*)(kbase + 32 * HD);
    const short8 kf3 = *(const short8*)(kbase + 48 * HD);
    const __hip_bfloat16* vbase = Vt + ((size_t)h * HD + lo16) * NROWS + c0 + quad * 8;
    const short8 vA0 = *(const short8*)(vbase);                 // d=lo16,    k 0..31
    const short8 vA1 = *(const short8*)(vbase + 32);            // d=lo16,    k 32..63
    const short8 vB0 = *(const short8*)(vbase + 16 * NROWS);    // d=16+lo16, k 0..31
    const short8 vB1 = *(const short8*)(vbase + 16 * NROWS + 32);

    const f32x4 z = {0.f, 0.f, 0.f, 0.f};
    __builtin_amdgcn_s_setprio(1);
    // swapped operands: S^T -> lane owns q-row lo16; k = c0 + g*16 + quad*4 + r
    f32x4 sv[4];
    sv[0] = __builtin_amdgcn_mfma_f32_16x16x32_bf16(kf0, qf, z, 0, 0, 0);
    sv[1] = __builtin_amdgcn_mfma_f32_16x16x32_bf16(kf1, qf, z, 0, 0, 0);
    sv[2] = __builtin_amdgcn_mfma_f32_16x16x32_bf16(kf2, qf, z, 0, 0, 0);
    sv[3] = __builtin_amdgcn_mfma_f32_16x16x32_bf16(kf3, qf, z, 0, 0, 0);
    __builtin_amdgcn_s_setprio(0);

    const int kb = c0 + quad * 4 - stq;
    float p[4][4];
    float mx = -3e38f;
    #pragma unroll
    for (int g = 0; g < 4; g++) {
      #pragma unroll
      for (int r = 0; r < 4; r++) {
        const float sc = ((unsigned)(kb + g * 16 + r) < rng) ? sv[g][r] * scale2 : -3e38f;
        p[g][r] = sc;
        mx = fmaxf(mx, sc);
      }
    }
    // reduce across the 4 lanes holding this q-row (bits 4,5 of lane id)
    mx = fmaxf(mx, __shfl_xor(mx, 16));
    mx = fmaxf(mx, __shfl_xor(mx, 32));
    const float nm = fmaxf(m, mx);
    float ps = 0.0f;
    #pragma unroll
    for (int g = 0; g < 4; g++) {
      #pragma unroll
      for (int r = 0; r < 4; r++) {
        p[g][r] = __builtin_amdgcn_exp2f(p[g][r] - nm);
        ps += p[g][r];
      }
    }
    ps += __shfl_xor(ps, 16);
    ps += __shfl_xor(ps, 32);

    const float alpha = __builtin_amdgcn_exp2f(m - nm);
    l = l * alpha + ps;
    if (!__all(nm == m)) {   // some row's max grew: rescale O (output-row layout)
      if (quad == 0) alds[lo16] = alpha;
      const f32x4 av = *(const f32x4*)&alds[quad * 4];
      #pragma unroll
      for (int r = 0; r < 4; r++) { o0[r] *= av[r]; o1[r] *= av[r]; }
    }
    m = nm;

    // P^T(lane) -> P(LDS): lane writes row q=lo16, cols g*16 + quad*4 + {0..3}
    #pragma unroll
    for (int g = 0; g < 4; g++) {
      __hip_bfloat162* pw = (__hip_bfloat162*)&Plds[lo16][g * 16 + quad * 4];
      __hip_bfloat162 a, b;
      a.x = __float2bfloat16(p[g][0]); a.y = __float2bfloat16(p[g][1]);
      b.x = __float2bfloat16(p[g][2]); b.y = __float2bfloat16(p[g][3]);
      pw[0] = a; pw[1] = b;
    }
    const short8 pf0 = *(const short8*)&Plds[lo16][quad * 8];        // k 0..31
    const short8 pf1 = *(const short8*)&Plds[lo16][32 + quad * 8];   // k 32..63
    __builtin_amdgcn_s_setprio(1);
    o0 = __builtin_amdgcn_mfma_f32_16x16x32_bf16(pf0, vA0, o0, 0, 0, 0);
    o0 = __builtin_amdgcn_mfma_f32_16x16x32_bf16(pf1, vA1, o0, 0, 0, 0);
    o1 = __builtin_amdgcn_mfma_f32_16x16x32_bf16(pf0, vB0, o1, 0, 0, 0);
    o1 = __builtin_amdgcn_mfma_f32_16x16x32_bf16(pf1, vB1, o1, 0, 0, 0);
    __builtin_amdgcn_s_setprio(0);
  }

  // ---- publish per-wave state ----
  #pragma unroll
  for (int r = 0; r < 4; r++) {
    const int row = quad * 4 + r;
    Old[wv][row][lo16]      = o0[r];
    Old[wv][row][lo16 + 16] = o1[r];
  }
  if (quad == 0) { mld[wv][lo16] = m; lld[wv][lo16] = l; }
  __syncthreads();

  // ---- merge: thread -> (row = tid>>4, cols {c, c+16}) ----
  const int row = threadIdx.x >> 4;
  const int c   = threadIdx.x & 15;
  float M = fmaxf(fmaxf(mld[0][row], mld[1][row]),
                  fmaxf(mld[2][row], mld[3][row]));
  float L = 0.f, O0 = 0.f, O1 = 0.f;
  #pragma unroll
  for (int w = 0; w < 4; w++) {
    const float e = __builtin_amdgcn_exp2f(mld[w][row] - M);
    L  += e * lld[w][row];
    O0 += e * Old[w][row][c];
    O1 += e * Old[w][row][c + 16];
  }
  const float inv = 1.0f / L;
  const int grow = r0 + row;
  out[(size_t)grow * DMODEL + h * HD + c]      = __float2bfloat16(O0 * inv);
  out[(size_t)grow * DMODEL + h * HD + 16 + c] = __float2bfloat16(O1 * inv);
}

// ---------------- out-proj + residual + LayerNorm (fused) ------------------
// 16x256 tile (row-complete), 4 waves; wave wv does cols [wv*64, +64).
// Direct-from-global frags (w_out bf16 is 128 KB, L2-resident per XCD).
__global__ __launch_bounds__(256, 4) void gemm_out_ln(
    const __hip_bfloat16* __restrict__ A,   // attnb [4096][256]
    const __hip_bfloat16* __restrict__ B,   // w_out bf16 [256][256]
    const float* __restrict__ bias,         // b_out
    const float* __restrict__ x,            // slots fp32 (residual)
    const float* __restrict__ gamma, const float* __restrict__ beta,
    float* __restrict__ out) {
  __shared__ float red1[16][4], red2[16][4];
  const int wv   = threadIdx.x >> 6;
  const int lane = threadIdx.x & 63;
  const int lo16 = lane & 15;
  const int quad = lane >> 4;
  const int r0 = blockIdx.x * 16;
  const int wn = wv * 64;

  f32x4 acc[4] = {};
  #pragma unroll
  for (int k0 = 0; k0 < 256; k0 += 32) {
    const short8 af = *(const short8*)(A + (size_t)(r0 + lo16) * 256 + k0 + quad * 8);
    #pragma unroll
    for (int ni = 0; ni < 4; ni++) {
      const short8 bf = *(const short8*)(B + (size_t)(wn + ni * 16 + lo16) * 256 + k0 + quad * 8);
      acc[ni] = __builtin_amdgcn_mfma_f32_16x16x32_bf16(af, bf, acc[ni], 0, 0, 0);
    }
  }

  // val = delta + bias + residual; per-row partial sums across this wave
  float val[4][4];
  float s1[4] = {}, s2[4] = {};
  #pragma unroll
  for (int ni = 0; ni < 4; ni++) {
    const int col = wn + ni * 16 + lo16;
    const float bv = bias[col];
    #pragma unroll
    for (int r = 0; r < 4; r++) {
      const int row = r0 + quad * 4 + r;
      const float v = acc[ni][r] + bv + x[(size_t)row * DMODEL + col];
      val[ni][r] = v;
      s1[r] += v;
      s2[r] += v * v;
    }
  }
  #pragma unroll
  for (int r = 0; r < 4; r++) {
    #pragma unroll
    for (int off = 1; off < 16; off <<= 1) {
      s1[r] += __shfl_xor(s1[r], off);
      s2[r] += __shfl_xor(s2[r], off);
    }
    if (lo16 == 0) { red1[quad * 4 + r][wv] = s1[r]; red2[quad * 4 + r][wv] = s2[r]; }
  }
  __syncthreads();
  #pragma unroll
  for (int r = 0; r < 4; r++) {
    const int lrow = quad * 4 + r;
    const float mean = (red1[lrow][0] + red1[lrow][1] + red1[lrow][2] + red1[lrow][3]) * (1.0f / DMODEL);
    const float ex2  = (red2[lrow][0] + red2[lrow][1] + red2[lrow][2] + red2[lrow][3]) * (1.0f / DMODEL);
    const float rstd = rsqrtf(fmaxf(ex2 - mean * mean, 0.0f) + 1e-5f);
    const int row = r0 + lrow;
    #pragma unroll
    for (int ni = 0; ni < 4; ni++) {
      const int col = wn + ni * 16 + lo16;
      out[(size_t)row * DMODEL + col] =
          (val[ni][r] - mean) * rstd * gamma[col] + beta[col];
    }
  }
}

extern "C" void kernel_launch(void* const* d_in, const int* in_sizes, int n_in,
                              void* d_out, int out_size, void* d_ws, size_t ws_size,
                              hipStream_t stream) {
  const float* slots  = (const float*)d_in[0];
  const int*   bidx   = (const int*)  d_in[1];
  const float* w_in   = (const float*)d_in[2];
  const float* b_in   = (const float*)d_in[3];
  const float* w_out  = (const float*)d_in[4];
  const float* b_out  = (const float*)d_in[5];
  const float* ln_g   = (const float*)d_in[6];
  const float* ln_b   = (const float*)d_in[7];
  float* out = (float*)d_out;

  char* ws = (char*)d_ws;
  __hip_bfloat16* Abf   = (__hip_bfloat16*)(ws);                 // 2 MB
  __hip_bfloat16* Qb    = (__hip_bfloat16*)(ws + (2u  << 20));   // 2 MB
  __hip_bfloat16* Kb    = (__hip_bfloat16*)(ws + (4u  << 20));   // 2 MB
  __hip_bfloat16* Vt    = (__hip_bfloat16*)(ws + (6u  << 20));   // 2 MB
  __hip_bfloat16* attnb = (__hip_bfloat16*)(ws + (8u  << 20));   // 2 MB
  __hip_bfloat16* Winb  = (__hip_bfloat16*)(ws + (10u << 20));   // 384 KB
  __hip_bfloat16* Woutb = (__hip_bfloat16*)(ws + (10u << 20) + (512u << 10)); // 128 KB
  int*            segs  = (int*)           (ws + (11u << 20));   // 32 ints

  // 0) fused casts + segment bounds
  prep_kernel<<<1296, 256, 0, stream>>>(slots, w_in, w_out, bidx,
                                        Abf, Winb, Woutb, segs);
  // 1) QKV projection -> scattered Q/K/Vt (bf16), 768 blocks (XCD-chunked)
  gemm_qkv<<<768, 256, 0, stream>>>(Abf, Winb, b_in, Qb, Kb, Vt);
  // 2) split-K flash attention, one block per (q-tile, head)
  attn_mfma<<<(NROWS / 16) * NHEADS, 256, 0, stream>>>(Qb, Kb, Vt, bidx,
                                                       segs, attnb);
  // 3) out-proj + residual + LayerNorm, 256 blocks
  gemm_out_ln<<<NROWS / 16, 256, 0, stream>>>(attnb, Woutb, b_out, slots,
                                              ln_g, ln_b, out);
}